// Round 3
// baseline (1549.526 us; speedup 1.0000x reference)
//
#include <hip/hip_runtime.h>
#include <math.h>

#define D 64
#define K 4096
// fp16 two-product scheme (round-9/round-1, field-tested absmax 0.0):
// e quantized to fp16 (rel 2^-11), z carried to ~2^-22 via hi/lo fp16 split.
// sigma(dq)~5e-3, worst contender delta ~0.04 -> MARGIN 0.08, ~2x headroom.
#define MARGIN 0.08f
#define KSPLIT 4
#define CPH (K / 16 / KSPLIT)  // chunks of 16 codes per half = 64

typedef float f32x4 __attribute__((ext_vector_type(4)));
typedef _Float16 f16x8 __attribute__((ext_vector_type(8)));

// ---------------------------------------------------------------------------
// Fused: esq[k] = sum_d emb[k][d]^2 (exact fp32, first 4096 threads) +
// fp16 emb copy PRE-SWIZZLED into MFMA B-fragment order:
// element (code k=c*16+col, dim d=t*32+quad*8+j) -> ((c*2+t)*64+quad*16+col)*8+j
// ---------------------------------------------------------------------------
__global__ __launch_bounds__(256) void esplit_kernel(const float* __restrict__ emb,
                                                     short* __restrict__ e_h,
                                                     float* __restrict__ e_sq) {
  int i = blockIdx.x * 256 + threadIdx.x;  // [0, 32768)
  {
    int lane = i & 63;
    int t = (i >> 6) & 1;
    int c = i >> 7;
    int quad = lane >> 4, col = lane & 15;
    const float* src = emb + (size_t)(c * 16 + col) * D + t * 32 + quad * 8;
    f32x4 u0 = *(const f32x4*)src;
    f32x4 u1 = *(const f32x4*)(src + 4);
    f16x8 h;
#pragma unroll
    for (int j = 0; j < 8; ++j) {
      float x = (j < 4) ? u0[j] : u1[j - 4];
      h[j] = (_Float16)x;
    }
    *(f16x8*)(e_h + (size_t)i * 8) = h;
  }
  if (i < K) {  // esq duty for the first 16 blocks
    const float* e = emb + (size_t)i * D;
    float s = 0.f;
#pragma unroll
    for (int d = 0; d < D; ++d) s = fmaf(e[d], e[d], s);
    e_sq[i] = s;
  }
}

// ---------------------------------------------------------------------------
// Barrier-free MFMA dist/argmin. Round-11: numerics are BYTE-IDENTICAL to the
// field-tested round-1 kernel (min-space, q = fmaf(-2,acc,esql), explicit
// chunk-id tracking, explicit index merge). Only SCHEDULING changed:
//  * depth-3 software prefetch, 4 statically-named B buffers, chunk loop
//    unrolled x4 (all buffer indices compile-time; rule-#20 safe). Round-1's
//    depth-1 left ~50% of dist as L2-latency stall (93us vs ~26us pipe work).
//  * launch_bounds(256,4): VGPR cap 128 vs ~112 static live set -> 4 waves/EU
//    (round-1 sat at ~42% occupancy). Round-8 spill cliff was ~120+ DEMAND;
//    cap 128 > demand 112 -> no spill.
//  * s_setprio(1) around the MFMA cluster (independent-wave regime, +4-7%).
// Round-10's index-packing is REVERTED (absmax 4066 field failure).
// A[m=lane&15][k=quad*8+j]; B[n=lane&15][k=quad*8+j]; C/D row=quad*4+r, col=lane&15.
// ---------------------------------------------------------------------------
#define MFMA16(A, B, C) __builtin_amdgcn_mfma_f32_16x16x32_f16(A, B, C, 0, 0, 0)

#define CHUNK(BX, BY, EQ, PFX, PFY, PFEQ, POFF, J)                           \
  {                                                                          \
    PFX = *(const f16x8*)(pB + (POFF) * 1024);                               \
    PFY = *(const f16x8*)(pB + (POFF) * 1024 + 512);                         \
    PFEQ = pE[(POFF) * 16];                                                  \
    f32x4 acc0 = {0.f, 0.f, 0.f, 0.f};                                       \
    f32x4 acc1 = {0.f, 0.f, 0.f, 0.f};                                       \
    __builtin_amdgcn_s_setprio(1);                                           \
    acc0 = MFMA16(a_hi[0][0], BX, acc0);                                     \
    acc1 = MFMA16(a_hi[1][0], BX, acc1);                                     \
    acc0 = MFMA16(a_lo[0][0], BX, acc0);                                     \
    acc1 = MFMA16(a_lo[1][0], BX, acc1);                                     \
    acc0 = MFMA16(a_hi[0][1], BY, acc0);                                     \
    acc1 = MFMA16(a_hi[1][1], BY, acc1);                                     \
    acc0 = MFMA16(a_lo[0][1], BY, acc0);                                     \
    acc1 = MFMA16(a_lo[1][1], BY, acc1);                                     \
    __builtin_amdgcn_s_setprio(0);                                           \
    const int cc_ = c4 + (J);                                                \
    _Pragma("unroll")                                                        \
    for (int r = 0; r < 4; ++r) {                                            \
      float q0 = fmaf(-2.f, acc0[r], EQ);                                    \
      float q1 = fmaf(-2.f, acc1[r], EQ);                                    \
      float ob0 = best[r], ob1 = best[4 + r];                                \
      best[r] = fminf(ob0, q0);                                              \
      best[4 + r] = fminf(ob1, q1);                                          \
      second[r] = __builtin_amdgcn_fmed3f(ob0, q0, second[r]);               \
      second[4 + r] = __builtin_amdgcn_fmed3f(ob1, q1, second[4 + r]);       \
      bidx[r] = (q0 < ob0) ? cc_ : bidx[r];                                  \
      bidx[4 + r] = (q1 < ob1) ? cc_ : bidx[4 + r];                          \
    }                                                                        \
  }

__global__ __launch_bounds__(256, 4) void dist_kernel(const float* __restrict__ z_e,
                                                      const short* __restrict__ e_h,
                                                      const float* __restrict__ esq,
                                                      float* __restrict__ pbest,
                                                      float* __restrict__ psec,
                                                      int* __restrict__ pidx) {
  const int tid = threadIdx.x;
  const int wv = tid >> 6;
  const int lane = tid & 63;
  const int quad = lane >> 4, col = lane & 15;
  const int rowbase = blockIdx.x * 128 + wv * 32;
  const int half = blockIdx.y;
  const int c0 = half * CPH;

  // ---- A fragments: 2 m-tiles x 2 k-halves, z split to fp16 hi/lo ----
  f16x8 a_hi[2][2], a_lo[2][2];
#pragma unroll
  for (int s = 0; s < 2; ++s) {
#pragma unroll
    for (int t = 0; t < 2; ++t) {
      const float* zr = z_e + (size_t)(rowbase + s * 16 + col) * D + t * 32 + quad * 8;
      f32x4 u0 = *(const f32x4*)zr;
      f32x4 u1 = *(const f32x4*)(zr + 4);
#pragma unroll
      for (int j = 0; j < 8; ++j) {
        float x = (j < 4) ? u0[j] : u1[j - 4];
        _Float16 h = (_Float16)x;
        a_hi[s][t][j] = h;
        a_lo[s][t][j] = (_Float16)(x - (float)h);
      }
    }
  }

  float best[8], second[8];
  int bidx[8];
#pragma unroll
  for (int i = 0; i < 8; ++i) {
    best[i] = __builtin_inff();
    second[i] = __builtin_inff();
    bidx[i] = 0;
  }

  const short* pB = e_h + (size_t)c0 * 1024 + (size_t)lane * 8;
  const float* pE = esq + c0 * 16 + col;

  // depth-3 prefetch prologue: chunks 0,1,2 in flight
  f16x8 B0x = *(const f16x8*)(pB);
  f16x8 B0y = *(const f16x8*)(pB + 512);
  f16x8 B1x = *(const f16x8*)(pB + 1024);
  f16x8 B1y = *(const f16x8*)(pB + 1536);
  f16x8 B2x = *(const f16x8*)(pB + 2048);
  f16x8 B2y = *(const f16x8*)(pB + 2560);
  f16x8 B3x, B3y;
  float eq0 = pE[0];
  float eq1 = pE[16];
  float eq2 = pE[32];
  float eq3;

  for (int c4 = 0; c4 < CPH; c4 += 4) {
    CHUNK(B0x, B0y, eq0, B3x, B3y, eq3, 3, 0)
    CHUNK(B1x, B1y, eq1, B0x, B0y, eq0, 4, 1)
    CHUNK(B2x, B2y, eq2, B1x, B1y, eq1, 5, 2)
    CHUNK(B3x, B3y, eq3, B2x, B2y, eq2, 6, 3)
    pB += 4096;
    pE += 64;
  }
  // (tail prefetches read <8KB past e_h into the workspace pad; discarded)

  // ---- merge across the 16 code-columns (xor over col bits) ----
#pragma unroll
  for (int i = 0; i < 8; ++i) {
    float b = best[i], s2 = second[i];
    int ix = (c0 + bidx[i]) * 16 + col;
#pragma unroll
    for (int off = 1; off < 16; off <<= 1) {
      float ob = __shfl_xor(b, off);
      float os = __shfl_xor(s2, off);
      int oi = __shfl_xor(ix, off);
      float ns = fminf(fminf(s2, os), fmaxf(b, ob));
      if (ob < b || (ob == b && oi < ix)) ix = oi;
      b = fminf(b, ob);
      s2 = ns;
    }
    if (col == 0) {
      int row = rowbase + (i >> 2) * 16 + quad * 4 + (i & 3);
      size_t o = (size_t)half * 65536 + row;
      pbest[o] = b;
      psec[o] = s2;
      pidx[o] = ix;
    }
  }
}

// ---------------------------------------------------------------------------
// Merge the KSPLIT partials per row; write best_idx; compact ambiguous rows
// (gap < MARGIN) into a worklist. Halves ascending, strict < -> first-occurrence.
// ---------------------------------------------------------------------------
__global__ __launch_bounds__(256) void merge_kernel(const float* __restrict__ pbest,
                                                    const float* __restrict__ psec,
                                                    const int* __restrict__ pidx,
                                                    int* __restrict__ best_idx,
                                                    int* __restrict__ worklist,
                                                    int* __restrict__ nwork,
                                                    int N) {
  int row = blockIdx.x * 256 + threadIdx.x;
  float b = pbest[row];
  float s2 = psec[row];
  int ix = pidx[row];
#pragma unroll
  for (int h = 1; h < KSPLIT; ++h) {
    size_t o = (size_t)h * 65536 + row;
    float bh = pbest[o];
    float sh = psec[o];
    int ih = pidx[o];
    s2 = fminf(fminf(s2, sh), fmaxf(b, bh));
    if (bh < b) ix = ih;  // strict <: ties keep lower-half (smaller) index
    b = fminf(b, bh);
  }
  best_idx[row] = ix;
  if (s2 - b < MARGIN) {
    int slot = atomicAdd(nwork, 1);
    worklist[slot] = row;
  }
}

// ---------------------------------------------------------------------------
// Candidate-based exact resolve (field-tested). Per ambiguous row: a half
// with second_h < B+MARGIN may hide an unknown contender -> exact fp32 scan
// of that 1024-code half. A half with best_h < B+MARGIN <= second_h has
// exactly one candidate -> one 256B dot.
// ---------------------------------------------------------------------------
__global__ __launch_bounds__(256, 1) void resolve_kernel(const float* __restrict__ z_e,
                                                         const float* __restrict__ emb,
                                                         const float* __restrict__ esq,
                                                         const float* __restrict__ pbest,
                                                         const float* __restrict__ psec,
                                                         const int* __restrict__ pidx,
                                                         const int* __restrict__ worklist,
                                                         const int* __restrict__ nwork,
                                                         int* __restrict__ best_idx) {
  const int tid = threadIdx.x;
  const int wave = tid >> 6;
  const int lane = tid & 63;
  const int wgid = blockIdx.x * 4 + wave;
  const int wstep = gridDim.x * 4;

  __shared__ float zs[4][D];
  const int n = *nwork;

  for (int j = wgid; j < n; j += wstep) {
    const int row = worklist[j];
    if (lane < 16) ((f32x4*)zs[wave])[lane] = *((const f32x4*)(z_e + (size_t)row * D) + lane);

    float pb[KSPLIT], ps[KSPLIT];
    int pi[KSPLIT];
    float B = __builtin_inff();
#pragma unroll
    for (int h = 0; h < KSPLIT; ++h) {
      size_t o = (size_t)h * 65536 + row;
      pb[h] = pbest[o];
      ps[h] = psec[o];
      pi[h] = pidx[o];
      B = fminf(B, pb[h]);
    }
    const float lim = B + MARGIN;

    float bv = __builtin_inff();
    int bi = 0;
#pragma unroll
    for (int h = 0; h < KSPLIT; ++h) {
      if (ps[h] < lim) {
        // exact fp32 scan of this 1024-code half
        float hb = __builtin_inff();
        int hx = 0;
        for (int t = 0; t < 16; ++t) {
          int c = h * 1024 + t * 64 + lane;
          const f32x4* er = (const f32x4*)(emb + (size_t)c * D);
          f32x4 a = {0.f, 0.f, 0.f, 0.f};
#pragma unroll
          for (int i = 0; i < 16; ++i)
            a = __builtin_elementwise_fma(er[i], ((const f32x4*)zs[wave])[i], a);
          float dot = (a[0] + a[1]) + (a[2] + a[3]);
          float q = fmaf(-2.f, dot, esq[c]);
          if (q < hb) { hb = q; hx = c; }  // ascending t => first occurrence
        }
#pragma unroll
        for (int off = 32; off > 0; off >>= 1) {
          float ov = __shfl_down(hb, off);
          int oi = __shfl_down(hx, off);
          if (ov < hb || (ov == hb && oi < hx)) { hb = ov; hx = oi; }
        }
        hb = __shfl(hb, 0);
        hx = __shfl(hx, 0);
        if (hb < bv || (hb == bv && hx < bi)) { bv = hb; bi = hx; }
      } else if (pb[h] < lim) {
        // single candidate: exact dot for code pi[h]
        int c = pi[h];
        float p = emb[(size_t)c * D + lane] * zs[wave][lane];
#pragma unroll
        for (int off = 1; off < 64; off <<= 1) p += __shfl_xor(p, off);
        float q = fmaf(-2.f, p, esq[c]);
        if (q < bv || (q == bv && c < bi)) { bv = q; bi = c; }
      }
    }
    if (lane == 0) best_idx[row] = bi;
  }
}

// ---------------------------------------------------------------------------
// Gather z_q, write z_q_st + indices, loss partials, histogram. Round-11:
// stats FUSED via last-block pattern. All cross-block data moves through
// ATOMICS only (counts re-read with atomicAdd(p,0), loss via a single float
// atomic accumulator) -> no plain-load coherence assumptions across XCDs.
// ---------------------------------------------------------------------------
__global__ __launch_bounds__(256) void finalize_kernel(const float* __restrict__ z_e,
                                                       const float* __restrict__ emb,
                                                       const int* __restrict__ best_idx,
                                                       float* __restrict__ out_zq,
                                                       float* __restrict__ out_idx,
                                                       int* __restrict__ counts,
                                                       int* __restrict__ done,
                                                       float* __restrict__ loss_accum,
                                                       float* __restrict__ out_scalars,
                                                       int N) {
  const int tid = threadIdx.x;
  const int wave = tid >> 6;
  const int lane = tid & 63;
  const int row = blockIdx.x * 4 + wave;

  int bidx = best_idx[row];
  float ze = z_e[(size_t)row * D + lane];
  float zq = emb[(size_t)bidx * D + lane];
  out_zq[(size_t)row * D + lane] = ze + (zq - ze);  // straight-through

  float diff = zq - ze;
  float sq = diff * diff;
#pragma unroll
  for (int off = 32; off > 0; off >>= 1) sq += __shfl_down(sq, off);

  __shared__ float ls[4];
  __shared__ int amlast;
  if (lane == 0) {
    ls[wave] = sq;
    out_idx[row] = (float)bidx;
    atomicAdd(&counts[bidx], 1);
  }
  __threadfence();   // each thread orders its own prior global ops (atomics)
  __syncthreads();   // all lane0 fences retired before tid0 signals
  if (tid == 0) {
    atomicAdd(loss_accum, ls[0] + ls[1] + ls[2] + ls[3]);
    __threadfence();
    amlast = (atomicAdd(done, 1) == (int)gridDim.x - 1);
  }
  __syncthreads();
  if (!amlast) return;

  // ---- last block: stats (reads via atomics only) ----
  float ent = 0.f;
  int act = 0;
  const float invN = 1.0f / (float)N;
  for (int k = tid; k < K; k += 256) {
    float p = (float)atomicAdd(&counts[k], 0) * invN;
    ent += p * logf(p + 1e-10f);
    act += (p > 0.001f) ? 1 : 0;
  }
#pragma unroll
  for (int off = 32; off > 0; off >>= 1) {
    ent += __shfl_down(ent, off);
    act += __shfl_down(act, off);
  }
  __shared__ float se[4];
  __shared__ int sa[4];
  if (lane == 0) { se[wave] = ent; sa[wave] = act; }
  __syncthreads();
  if (tid == 0) {
    float L = atomicAdd(loss_accum, 0.f);  // atomic read of the full sum
    float E = se[0] + se[1] + se[2] + se[3];
    int A = sa[0] + sa[1] + sa[2] + sa[3];
    out_scalars[0] = 0.25f * L / ((float)N * (float)D);  // commitment loss
    out_scalars[1] = expf(-E);                            // perplexity
    out_scalars[2] = (float)A;                            // n_active
  }
}

extern "C" void kernel_launch(void* const* d_in, const int* in_sizes, int n_in,
                              void* d_out, int out_size, void* d_ws, size_t ws_size,
                              hipStream_t stream) {
  const float* z_e = (const float*)d_in[0];
  const float* emb = (const float*)d_in[1];
  const int N = in_sizes[0] / D;  // 65536

  float* out = (float*)d_out;
  float* out_zq = out;
  float* out_idx = out + (size_t)N * D;
  float* out_scalars = out + (size_t)N * (D + 1);

  char* ws = (char*)d_ws;
  size_t o = 0;
  int* counts = (int*)(ws + o);      o += 16384;                  // 4096 ints
  int* ctrl = (int*)(ws + o);        o += 256;                    // nwork/done/loss
  int* nwork = ctrl;
  int* done = ctrl + 1;
  float* loss_accum = (float*)(ctrl + 2);
  float* esq = (float*)(ws + o);     o += 16384;                  // 4096 f32
  short* e_h = (short*)(ws + o);     o += (size_t)K * D * 2;      // 512 KB (fp16)
  o += 8192;                                                      // prefetch pad
  float* pbest = (float*)(ws + o);   o += (size_t)KSPLIT * N * 4; // 1 MB
  float* psec = (float*)(ws + o);    o += (size_t)KSPLIT * N * 4; // 1 MB
  int* pidx = (int*)(ws + o);        o += (size_t)KSPLIT * N * 4; // 1 MB
  int* best_idx = (int*)(ws + o);    o += (size_t)N * 4;          // 256 KB
  int* worklist = (int*)(ws + o);    o += (size_t)N * 4;          // 256 KB

  hipMemsetAsync(counts, 0, 16384 + 256, stream);  // counts + ctrl block

  esplit_kernel<<<(K / 16) * 2 * 64 / 256, 256, 0, stream>>>(emb, e_h, esq);
  dist_kernel<<<dim3(N / 128, KSPLIT), 256, 0, stream>>>(z_e, e_h, esq,
                                                         pbest, psec, pidx);
  merge_kernel<<<N / 256, 256, 0, stream>>>(pbest, psec, pidx, best_idx,
                                            worklist, nwork, N);
  resolve_kernel<<<512, 256, 0, stream>>>(z_e, emb, esq, pbest, psec, pidx,
                                          worklist, nwork, best_idx);
  finalize_kernel<<<N / 4, 256, 0, stream>>>(z_e, emb, best_idx, out_zq, out_idx,
                                             counts, done, loss_accum,
                                             out_scalars, N);
}

// Round 4
// 238.908 us; speedup vs baseline: 6.4859x; 6.4859x over previous
//
#include <hip/hip_runtime.h>
#include <math.h>

#define D 64
#define K 4096
// fp16 two-product scheme (round-9/round-1, field-tested absmax 0.0):
// e quantized to fp16 (rel 2^-11), z carried to ~2^-22 via hi/lo fp16 split.
// sigma(dq)~5e-3, worst contender delta ~0.04 -> MARGIN 0.08, ~2x headroom.
#define MARGIN 0.08f
#define KSPLIT 4
#define CPH (K / 16 / KSPLIT)  // chunks of 16 codes per half = 64

typedef float f32x4 __attribute__((ext_vector_type(4)));
typedef _Float16 f16x8 __attribute__((ext_vector_type(8)));

// ---------------------------------------------------------------------------
// Fused: esq[k] = sum_d emb[k][d]^2 (exact fp32, first 4096 threads) +
// fp16 emb copy PRE-SWIZZLED into MFMA B-fragment order:
// element (code k=c*16+col, dim d=t*32+quad*8+j) -> ((c*2+t)*64+quad*16+col)*8+j
// ---------------------------------------------------------------------------
__global__ __launch_bounds__(256) void esplit_kernel(const float* __restrict__ emb,
                                                     short* __restrict__ e_h,
                                                     float* __restrict__ e_sq) {
  int i = blockIdx.x * 256 + threadIdx.x;  // [0, 32768)
  {
    int lane = i & 63;
    int t = (i >> 6) & 1;
    int c = i >> 7;
    int quad = lane >> 4, col = lane & 15;
    const float* src = emb + (size_t)(c * 16 + col) * D + t * 32 + quad * 8;
    f32x4 u0 = *(const f32x4*)src;
    f32x4 u1 = *(const f32x4*)(src + 4);
    f16x8 h;
#pragma unroll
    for (int j = 0; j < 8; ++j) {
      float x = (j < 4) ? u0[j] : u1[j - 4];
      h[j] = (_Float16)x;
    }
    *(f16x8*)(e_h + (size_t)i * 8) = h;
  }
  if (i < K) {  // esq duty for the first 16 blocks
    const float* e = emb + (size_t)i * D;
    float s = 0.f;
#pragma unroll
    for (int d = 0; d < D; ++d) s = fmaf(e[d], e[d], s);
    e_sq[i] = s;
  }
}

// ---------------------------------------------------------------------------
// Barrier-free MFMA dist/argmin. Numerics BYTE-IDENTICAL to the field-tested
// round-1 kernel (min-space, q = fmaf(-2,acc,esql), explicit chunk-id
// tracking, explicit index merge). Scheduling (round-3, field-passed):
//  * depth-3 software prefetch, 4 statically-named B buffers, x4 unroll.
//  * launch_bounds(256,4): VGPR cap 128 vs ~112 static live set.
//  * s_setprio(1) around the MFMA cluster.
// A[m=lane&15][k=quad*8+j]; B[n=lane&15][k=quad*8+j]; C/D row=quad*4+r, col=lane&15.
// ---------------------------------------------------------------------------
#define MFMA16(A, B, C) __builtin_amdgcn_mfma_f32_16x16x32_f16(A, B, C, 0, 0, 0)

#define CHUNK(BX, BY, EQ, PFX, PFY, PFEQ, POFF, J)                           \
  {                                                                          \
    PFX = *(const f16x8*)(pB + (POFF) * 1024);                               \
    PFY = *(const f16x8*)(pB + (POFF) * 1024 + 512);                         \
    PFEQ = pE[(POFF) * 16];                                                  \
    f32x4 acc0 = {0.f, 0.f, 0.f, 0.f};                                       \
    f32x4 acc1 = {0.f, 0.f, 0.f, 0.f};                                       \
    __builtin_amdgcn_s_setprio(1);                                           \
    acc0 = MFMA16(a_hi[0][0], BX, acc0);                                     \
    acc1 = MFMA16(a_hi[1][0], BX, acc1);                                     \
    acc0 = MFMA16(a_lo[0][0], BX, acc0);                                     \
    acc1 = MFMA16(a_lo[1][0], BX, acc1);                                     \
    acc0 = MFMA16(a_hi[0][1], BY, acc0);                                     \
    acc1 = MFMA16(a_hi[1][1], BY, acc1);                                     \
    acc0 = MFMA16(a_lo[0][1], BY, acc0);                                     \
    acc1 = MFMA16(a_lo[1][1], BY, acc1);                                     \
    __builtin_amdgcn_s_setprio(0);                                           \
    const int cc_ = c4 + (J);                                                \
    _Pragma("unroll")                                                        \
    for (int r = 0; r < 4; ++r) {                                            \
      float q0 = fmaf(-2.f, acc0[r], EQ);                                    \
      float q1 = fmaf(-2.f, acc1[r], EQ);                                    \
      float ob0 = best[r], ob1 = best[4 + r];                                \
      best[r] = fminf(ob0, q0);                                              \
      best[4 + r] = fminf(ob1, q1);                                          \
      second[r] = __builtin_amdgcn_fmed3f(ob0, q0, second[r]);               \
      second[4 + r] = __builtin_amdgcn_fmed3f(ob1, q1, second[4 + r]);       \
      bidx[r] = (q0 < ob0) ? cc_ : bidx[r];                                  \
      bidx[4 + r] = (q1 < ob1) ? cc_ : bidx[4 + r];                          \
    }                                                                        \
  }

__global__ __launch_bounds__(256, 4) void dist_kernel(const float* __restrict__ z_e,
                                                      const short* __restrict__ e_h,
                                                      const float* __restrict__ esq,
                                                      float* __restrict__ pbest,
                                                      float* __restrict__ psec,
                                                      int* __restrict__ pidx) {
  const int tid = threadIdx.x;
  const int wv = tid >> 6;
  const int lane = tid & 63;
  const int quad = lane >> 4, col = lane & 15;
  const int rowbase = blockIdx.x * 128 + wv * 32;
  const int half = blockIdx.y;
  const int c0 = half * CPH;

  // ---- A fragments: 2 m-tiles x 2 k-halves, z split to fp16 hi/lo ----
  f16x8 a_hi[2][2], a_lo[2][2];
#pragma unroll
  for (int s = 0; s < 2; ++s) {
#pragma unroll
    for (int t = 0; t < 2; ++t) {
      const float* zr = z_e + (size_t)(rowbase + s * 16 + col) * D + t * 32 + quad * 8;
      f32x4 u0 = *(const f32x4*)zr;
      f32x4 u1 = *(const f32x4*)(zr + 4);
#pragma unroll
      for (int j = 0; j < 8; ++j) {
        float x = (j < 4) ? u0[j] : u1[j - 4];
        _Float16 h = (_Float16)x;
        a_hi[s][t][j] = h;
        a_lo[s][t][j] = (_Float16)(x - (float)h);
      }
    }
  }

  float best[8], second[8];
  int bidx[8];
#pragma unroll
  for (int i = 0; i < 8; ++i) {
    best[i] = __builtin_inff();
    second[i] = __builtin_inff();
    bidx[i] = 0;
  }

  const short* pB = e_h + (size_t)c0 * 1024 + (size_t)lane * 8;
  const float* pE = esq + c0 * 16 + col;

  // depth-3 prefetch prologue: chunks 0,1,2 in flight
  f16x8 B0x = *(const f16x8*)(pB);
  f16x8 B0y = *(const f16x8*)(pB + 512);
  f16x8 B1x = *(const f16x8*)(pB + 1024);
  f16x8 B1y = *(const f16x8*)(pB + 1536);
  f16x8 B2x = *(const f16x8*)(pB + 2048);
  f16x8 B2y = *(const f16x8*)(pB + 2560);
  f16x8 B3x, B3y;
  float eq0 = pE[0];
  float eq1 = pE[16];
  float eq2 = pE[32];
  float eq3;

  for (int c4 = 0; c4 < CPH; c4 += 4) {
    CHUNK(B0x, B0y, eq0, B3x, B3y, eq3, 3, 0)
    CHUNK(B1x, B1y, eq1, B0x, B0y, eq0, 4, 1)
    CHUNK(B2x, B2y, eq2, B1x, B1y, eq1, 5, 2)
    CHUNK(B3x, B3y, eq3, B2x, B2y, eq2, 6, 3)
    pB += 4096;
    pE += 64;
  }
  // (tail prefetches read <8KB past e_h into the workspace pad; discarded)

  // ---- merge across the 16 code-columns (xor over col bits) ----
#pragma unroll
  for (int i = 0; i < 8; ++i) {
    float b = best[i], s2 = second[i];
    int ix = (c0 + bidx[i]) * 16 + col;
#pragma unroll
    for (int off = 1; off < 16; off <<= 1) {
      float ob = __shfl_xor(b, off);
      float os = __shfl_xor(s2, off);
      int oi = __shfl_xor(ix, off);
      float ns = fminf(fminf(s2, os), fmaxf(b, ob));
      if (ob < b || (ob == b && oi < ix)) ix = oi;
      b = fminf(b, ob);
      s2 = ns;
    }
    if (col == 0) {
      int row = rowbase + (i >> 2) * 16 + quad * 4 + (i & 3);
      size_t o = (size_t)half * 65536 + row;
      pbest[o] = b;
      psec[o] = s2;
      pidx[o] = ix;
    }
  }
}

// ---------------------------------------------------------------------------
// Merge the KSPLIT partials per row; write best_idx; compact ambiguous rows
// (gap < MARGIN) into a worklist. Halves ascending, strict < -> first-occurrence.
// ---------------------------------------------------------------------------
__global__ __launch_bounds__(256) void merge_kernel(const float* __restrict__ pbest,
                                                    const float* __restrict__ psec,
                                                    const int* __restrict__ pidx,
                                                    int* __restrict__ best_idx,
                                                    int* __restrict__ worklist,
                                                    int* __restrict__ nwork,
                                                    int N) {
  int row = blockIdx.x * 256 + threadIdx.x;
  float b = pbest[row];
  float s2 = psec[row];
  int ix = pidx[row];
#pragma unroll
  for (int h = 1; h < KSPLIT; ++h) {
    size_t o = (size_t)h * 65536 + row;
    float bh = pbest[o];
    float sh = psec[o];
    int ih = pidx[o];
    s2 = fminf(fminf(s2, sh), fmaxf(b, bh));
    if (bh < b) ix = ih;  // strict <: ties keep lower-half (smaller) index
    b = fminf(b, bh);
  }
  best_idx[row] = ix;
  if (s2 - b < MARGIN) {
    int slot = atomicAdd(nwork, 1);
    worklist[slot] = row;
  }
}

// ---------------------------------------------------------------------------
// Candidate-based exact resolve (field-tested). Per ambiguous row: a half
// with second_h < B+MARGIN may hide an unknown contender -> exact fp32 scan
// of that 1024-code half. A half with best_h < B+MARGIN <= second_h has
// exactly one candidate -> one 256B dot.
// ---------------------------------------------------------------------------
__global__ __launch_bounds__(256, 1) void resolve_kernel(const float* __restrict__ z_e,
                                                         const float* __restrict__ emb,
                                                         const float* __restrict__ esq,
                                                         const float* __restrict__ pbest,
                                                         const float* __restrict__ psec,
                                                         const int* __restrict__ pidx,
                                                         const int* __restrict__ worklist,
                                                         const int* __restrict__ nwork,
                                                         int* __restrict__ best_idx) {
  const int tid = threadIdx.x;
  const int wave = tid >> 6;
  const int lane = tid & 63;
  const int wgid = blockIdx.x * 4 + wave;
  const int wstep = gridDim.x * 4;

  __shared__ float zs[4][D];
  const int n = *nwork;

  for (int j = wgid; j < n; j += wstep) {
    const int row = worklist[j];
    if (lane < 16) ((f32x4*)zs[wave])[lane] = *((const f32x4*)(z_e + (size_t)row * D) + lane);

    float pb[KSPLIT], ps[KSPLIT];
    int pi[KSPLIT];
    float B = __builtin_inff();
#pragma unroll
    for (int h = 0; h < KSPLIT; ++h) {
      size_t o = (size_t)h * 65536 + row;
      pb[h] = pbest[o];
      ps[h] = psec[o];
      pi[h] = pidx[o];
      B = fminf(B, pb[h]);
    }
    const float lim = B + MARGIN;

    float bv = __builtin_inff();
    int bi = 0;
#pragma unroll
    for (int h = 0; h < KSPLIT; ++h) {
      if (ps[h] < lim) {
        // exact fp32 scan of this 1024-code half
        float hb = __builtin_inff();
        int hx = 0;
        for (int t = 0; t < 16; ++t) {
          int c = h * 1024 + t * 64 + lane;
          const f32x4* er = (const f32x4*)(emb + (size_t)c * D);
          f32x4 a = {0.f, 0.f, 0.f, 0.f};
#pragma unroll
          for (int i = 0; i < 16; ++i)
            a = __builtin_elementwise_fma(er[i], ((const f32x4*)zs[wave])[i], a);
          float dot = (a[0] + a[1]) + (a[2] + a[3]);
          float q = fmaf(-2.f, dot, esq[c]);
          if (q < hb) { hb = q; hx = c; }  // ascending t => first occurrence
        }
#pragma unroll
        for (int off = 32; off > 0; off >>= 1) {
          float ov = __shfl_down(hb, off);
          int oi = __shfl_down(hx, off);
          if (ov < hb || (ov == hb && oi < hx)) { hb = ov; hx = oi; }
        }
        hb = __shfl(hb, 0);
        hx = __shfl(hx, 0);
        if (hb < bv || (hb == bv && hx < bi)) { bv = hb; bi = hx; }
      } else if (pb[h] < lim) {
        // single candidate: exact dot for code pi[h]
        int c = pi[h];
        float p = emb[(size_t)c * D + lane] * zs[wave][lane];
#pragma unroll
        for (int off = 1; off < 64; off <<= 1) p += __shfl_xor(p, off);
        float q = fmaf(-2.f, p, esq[c]);
        if (q < bv || (q == bv && c < bi)) { bv = q; bi = c; }
      }
    }
    if (lane == 0) best_idx[row] = bi;
  }
}

// ---------------------------------------------------------------------------
// Gather z_q, write z_q_st + indices, loss partials, histogram.
// (Round-3's last-block stats fusion REVERTED: per-thread __threadfence +
// 16K-block single-address atomics serialized to 1350us. Fusion cost must be
// O(blocks), never O(threads).)
// ---------------------------------------------------------------------------
__global__ __launch_bounds__(256) void finalize_kernel(const float* __restrict__ z_e,
                                                       const float* __restrict__ emb,
                                                       const int* __restrict__ best_idx,
                                                       float* __restrict__ out_zq,
                                                       float* __restrict__ out_idx,
                                                       int* __restrict__ counts,
                                                       float* __restrict__ block_loss) {
  const int tid = threadIdx.x;
  const int wave = tid >> 6;
  const int lane = tid & 63;
  const int row = blockIdx.x * 4 + wave;

  int bidx = best_idx[row];
  float ze = z_e[(size_t)row * D + lane];
  float zq = emb[(size_t)bidx * D + lane];
  float st = ze + (zq - ze);  // straight-through, same formula as reference
  out_zq[(size_t)row * D + lane] = st;

  float diff = zq - ze;
  float sq = diff * diff;
#pragma unroll
  for (int off = 32; off > 0; off >>= 1) sq += __shfl_down(sq, off);

  __shared__ float ls[4];
  if (lane == 0) {
    ls[wave] = sq;
    out_idx[row] = (float)bidx;
    atomicAdd(&counts[bidx], 1);
  }
  __syncthreads();
  if (tid == 0) block_loss[blockIdx.x] = ls[0] + ls[1] + ls[2] + ls[3];
}

// ---------------------------------------------------------------------------
// Final scalars: commitment loss, perplexity, n_active. Single block.
// ---------------------------------------------------------------------------
__global__ __launch_bounds__(1024) void stats_kernel(const float* __restrict__ block_loss,
                                                     int nblocks,
                                                     const int* __restrict__ counts,
                                                     float* __restrict__ out_scalars,
                                                     int N) {
  const int tid = threadIdx.x;
  const int wave = tid >> 6;
  const int lane = tid & 63;

  float lsum = 0.f;
  for (int i = tid; i < nblocks; i += 1024) lsum += block_loss[i];

  float ent = 0.f;
  int act = 0;
  const float invN = 1.0f / (float)N;
  for (int k = tid; k < K; k += 1024) {
    float p = (float)counts[k] * invN;
    ent += p * logf(p + 1e-10f);
    act += (p > 0.001f) ? 1 : 0;
  }

#pragma unroll
  for (int off = 32; off > 0; off >>= 1) {
    lsum += __shfl_down(lsum, off);
    ent += __shfl_down(ent, off);
    act += __shfl_down(act, off);
  }

  __shared__ float sl[16], se[16];
  __shared__ int sa[16];
  if (lane == 0) { sl[wave] = lsum; se[wave] = ent; sa[wave] = act; }
  __syncthreads();
  if (tid == 0) {
    float L = 0.f, E = 0.f;
    int A = 0;
#pragma unroll
    for (int w = 0; w < 16; ++w) { L += sl[w]; E += se[w]; A += sa[w]; }
    out_scalars[0] = 0.25f * L / ((float)N * (float)D);  // commitment loss
    out_scalars[1] = expf(-E);                            // perplexity
    out_scalars[2] = (float)A;                            // n_active
  }
}

extern "C" void kernel_launch(void* const* d_in, const int* in_sizes, int n_in,
                              void* d_out, int out_size, void* d_ws, size_t ws_size,
                              hipStream_t stream) {
  const float* z_e = (const float*)d_in[0];
  const float* emb = (const float*)d_in[1];
  const int N = in_sizes[0] / D;  // 65536

  float* out = (float*)d_out;
  float* out_zq = out;
  float* out_idx = out + (size_t)N * D;
  float* out_scalars = out + (size_t)N * (D + 1);

  char* ws = (char*)d_ws;
  size_t o = 0;
  int* counts = (int*)(ws + o);      o += 16384;                  // 4096 ints
  int* nwork = (int*)(ws + o);       o += 256;                    // 1 int (+pad)
  float* esq = (float*)(ws + o);     o += 16384;                  // 4096 f32
  short* e_h = (short*)(ws + o);     o += (size_t)K * D * 2;      // 512 KB (fp16)
  o += 8192;                                                      // prefetch pad
  float* pbest = (float*)(ws + o);   o += (size_t)KSPLIT * N * 4; // 1 MB
  float* psec = (float*)(ws + o);    o += (size_t)KSPLIT * N * 4; // 1 MB
  int* pidx = (int*)(ws + o);        o += (size_t)KSPLIT * N * 4; // 1 MB
  int* best_idx = (int*)(ws + o);    o += (size_t)N * 4;          // 256 KB
  int* worklist = (int*)(ws + o);    o += (size_t)N * 4;          // 256 KB
  float* block_loss = (float*)(ws + o);                            // 64 KB

  hipMemsetAsync(counts, 0, 16384 + 256, stream);  // counts + nwork

  esplit_kernel<<<(K / 16) * 2 * 64 / 256, 256, 0, stream>>>(emb, e_h, esq);
  dist_kernel<<<dim3(N / 128, KSPLIT), 256, 0, stream>>>(z_e, e_h, esq,
                                                         pbest, psec, pidx);
  merge_kernel<<<N / 256, 256, 0, stream>>>(pbest, psec, pidx, best_idx,
                                            worklist, nwork, N);
  resolve_kernel<<<512, 256, 0, stream>>>(z_e, emb, esq, pbest, psec, pidx,
                                          worklist, nwork, best_idx);
  finalize_kernel<<<N / 4, 256, 0, stream>>>(z_e, emb, best_idx, out_zq, out_idx,
                                             counts, block_loss);
  stats_kernel<<<1, 1024, 0, stream>>>(block_loss, N / 4, counts, out_scalars, N);
}

// Round 5
// 224.860 us; speedup vs baseline: 6.8911x; 1.0625x over previous
//
#include <hip/hip_runtime.h>
#include <math.h>

#define D 64
#define K 4096
// fp16 two-product scheme (field-tested absmax 0.0): e quantized to fp16
// (rel 2^-11), z carried to ~2^-22 via hi/lo fp16 split. sigma(dq)~5e-3,
// worst contender delta ~0.04 -> MARGIN 0.08, ~2x headroom. Round-5's
// seed-trick adds only rounding-order noise (~1e-5).
#define MARGIN 0.08f
#define KSPLIT 4
#define CPH (K / 16 / KSPLIT)  // chunks of 16 codes per half = 64

typedef float f32x4 __attribute__((ext_vector_type(4)));
typedef _Float16 f16x8 __attribute__((ext_vector_type(8)));

// ---------------------------------------------------------------------------
// Fused: counts zeroing (kills the memset node) + esq[k] = sum_d emb[k][d]^2
// (exact fp32) + fp16 emb copy PRE-SWIZZLED into MFMA B-fragment order:
// element (code k=c*16+col, dim d=t*32+quad*8+j) -> ((c*2+t)*64+quad*16+col)*8+j
// ---------------------------------------------------------------------------
__global__ __launch_bounds__(256) void esplit_kernel(const float* __restrict__ emb,
                                                     short* __restrict__ e_h,
                                                     float* __restrict__ e_sq,
                                                     int* __restrict__ counts) {
  int i = blockIdx.x * 256 + threadIdx.x;  // [0, 32768)
  {
    int lane = i & 63;
    int t = (i >> 6) & 1;
    int c = i >> 7;
    int quad = lane >> 4, col = lane & 15;
    const float* src = emb + (size_t)(c * 16 + col) * D + t * 32 + quad * 8;
    f32x4 u0 = *(const f32x4*)src;
    f32x4 u1 = *(const f32x4*)(src + 4);
    f16x8 h;
#pragma unroll
    for (int j = 0; j < 8; ++j) {
      float x = (j < 4) ? u0[j] : u1[j - 4];
      h[j] = (_Float16)x;
    }
    *(f16x8*)(e_h + (size_t)i * 8) = h;
  }
  if (i < K) {  // esq + counts duty for the first 16 blocks
    counts[i] = 0;
    const float* e = emb + (size_t)i * D;
    float s = 0.f;
#pragma unroll
    for (int d = 0; d < D; ++d) s = fmaf(e[d], e[d], s);
    e_sq[i] = s;
  }
}

// ---------------------------------------------------------------------------
// Barrier-free MFMA dist/argmin. Structure = EXACT round-1 (93us known-good:
// depth-1 prefetch, VGPR~48, no spills; round-4's depth-3 unroll spilled ->
// 17.5MB scratch writes, REVERTED). One numeric delta vs round-1:
//  * acc seeded with -esq/2; track MAX of acc (== min of q); q-space
//    conversion once in the epilogue. Deletes the per-distance fmaf
//    (round-1 VALU was the bottleneck pipe: 64% busy = 60us of 93).
//    Explicit per-chunk index tracking KEPT (round-2's packed-index variant
//    failed; this isolates seed/max-space from packing).
// A[m=lane&15][k=quad*8+j]; B[n=lane&15][k=quad*8+j]; C/D row=quad*4+r, col=lane&15.
// ---------------------------------------------------------------------------
__global__ __launch_bounds__(256, 2) void dist_kernel(const float* __restrict__ z_e,
                                                      const short* __restrict__ e_h,
                                                      const float* __restrict__ esq,
                                                      float* __restrict__ pbest,
                                                      float* __restrict__ psec,
                                                      int* __restrict__ pidx) {
  const int tid = threadIdx.x;
  const int wv = tid >> 6;
  const int lane = tid & 63;
  const int quad = lane >> 4, col = lane & 15;
  const int rowbase = blockIdx.x * 128 + wv * 32;
  const int half = blockIdx.y;
  const int c0 = half * CPH;

  // ---- A fragments: 2 m-tiles x 2 k-halves, z split to fp16 hi/lo ----
  f16x8 a_hi[2][2], a_lo[2][2];
#pragma unroll
  for (int s = 0; s < 2; ++s) {
#pragma unroll
    for (int t = 0; t < 2; ++t) {
      const float* zr = z_e + (size_t)(rowbase + s * 16 + col) * D + t * 32 + quad * 8;
      f32x4 u0 = *(const f32x4*)zr;
      f32x4 u1 = *(const f32x4*)(zr + 4);
#pragma unroll
      for (int j = 0; j < 8; ++j) {
        float x = (j < 4) ? u0[j] : u1[j - 4];
        _Float16 h = (_Float16)x;
        a_hi[s][t][j] = h;
        a_lo[s][t][j] = (_Float16)(x - (float)h);
      }
    }
  }

  // Max-space tracking: acc = dot - esq/2; larger acc == smaller q = -2*acc.
  float best[8], second[8];
  int bidx[8];
#pragma unroll
  for (int i = 0; i < 8; ++i) {
    best[i] = -__builtin_inff();
    second[i] = -__builtin_inff();
    bidx[i] = 0;
  }

  const size_t lofs = (size_t)lane * 8;
  const short* pB = e_h + (size_t)c0 * 1024 + lofs;
  const float* pE = esq + c0 * 16 + col;
  f16x8 b0 = *(const f16x8*)pB;
  f16x8 b1 = *(const f16x8*)(pB + 512);
  float eq = *pE;

  for (int cc = 0; cc < CPH; ++cc) {
    // depth-1 prefetch of next chunk (tail reads <2KB into the workspace pad)
    pB += 1024;
    pE += 16;
    f16x8 n0 = *(const f16x8*)pB;
    f16x8 n1 = *(const f16x8*)(pB + 512);
    float neq = *pE;

    const float seed = -0.5f * eq;
    f32x4 acc0 = {seed, seed, seed, seed};
    f32x4 acc1 = {seed, seed, seed, seed};
    acc0 = __builtin_amdgcn_mfma_f32_16x16x32_f16(a_hi[0][0], b0, acc0, 0, 0, 0);
    acc1 = __builtin_amdgcn_mfma_f32_16x16x32_f16(a_hi[1][0], b0, acc1, 0, 0, 0);
    acc0 = __builtin_amdgcn_mfma_f32_16x16x32_f16(a_lo[0][0], b0, acc0, 0, 0, 0);
    acc1 = __builtin_amdgcn_mfma_f32_16x16x32_f16(a_lo[1][0], b0, acc1, 0, 0, 0);
    acc0 = __builtin_amdgcn_mfma_f32_16x16x32_f16(a_hi[0][1], b1, acc0, 0, 0, 0);
    acc1 = __builtin_amdgcn_mfma_f32_16x16x32_f16(a_hi[1][1], b1, acc1, 0, 0, 0);
    acc0 = __builtin_amdgcn_mfma_f32_16x16x32_f16(a_lo[0][1], b1, acc0, 0, 0, 0);
    acc1 = __builtin_amdgcn_mfma_f32_16x16x32_f16(a_lo[1][1], b1, acc1, 0, 0, 0);

#pragma unroll
    for (int r = 0; r < 4; ++r) {
      float a0 = acc0[r];
      float ob = best[r];
      best[r] = fmaxf(ob, a0);
      second[r] = __builtin_amdgcn_fmed3f(ob, a0, second[r]);
      bidx[r] = (a0 > ob) ? cc : bidx[r];  // strict >: ties keep earlier chunk
    }
#pragma unroll
    for (int r = 0; r < 4; ++r) {
      float a1 = acc1[r];
      float ob = best[4 + r];
      best[4 + r] = fmaxf(ob, a1);
      second[4 + r] = __builtin_amdgcn_fmed3f(ob, a1, second[4 + r]);
      bidx[4 + r] = (a1 > ob) ? cc : bidx[4 + r];
    }

    b0 = n0;
    b1 = n1;
    eq = neq;
  }

  // ---- convert to q-space, merge across the 16 code-columns ----
#pragma unroll
  for (int i = 0; i < 8; ++i) {
    float b = -2.f * best[i];
    float s2 = -2.f * second[i];
    int ix = (c0 + bidx[i]) * 16 + col;
#pragma unroll
    for (int off = 1; off < 16; off <<= 1) {
      float ob = __shfl_xor(b, off);
      float os = __shfl_xor(s2, off);
      int oi = __shfl_xor(ix, off);
      float ns = fminf(fminf(s2, os), fmaxf(b, ob));
      if (ob < b || (ob == b && oi < ix)) ix = oi;
      b = fminf(b, ob);
      s2 = ns;
    }
    if (col == 0) {
      int row = rowbase + (i >> 2) * 16 + quad * 4 + (i & 3);
      size_t o = (size_t)half * 65536 + row;
      pbest[o] = b;
      psec[o] = s2;
      pidx[o] = ix;
    }
  }
}

// ---------------------------------------------------------------------------
// FUSED merge + resolve (saves a node + the global worklist round-trip).
// Phase 1: per-thread KSPLIT merge (math identical to field-tested merge),
// ambiguous rows (gap < MARGIN) go to a block-local LDS worklist (~6/block
// expected at MARGIN 0.08). Phase 2: the block's 4 waves cooperatively run
// the field-tested candidate-based exact resolve on the local list.
// ---------------------------------------------------------------------------
__global__ __launch_bounds__(256) void merge_resolve_kernel(const float* __restrict__ z_e,
                                                            const float* __restrict__ emb,
                                                            const float* __restrict__ esq,
                                                            const float* __restrict__ pbest,
                                                            const float* __restrict__ psec,
                                                            const int* __restrict__ pidx,
                                                            int* __restrict__ best_idx) {
  const int tid = threadIdx.x;
  __shared__ int wl[256];
  __shared__ int wn;
  __shared__ float zs[4][D];
  if (tid == 0) wn = 0;
  __syncthreads();

  {
    int row = blockIdx.x * 256 + tid;
    float b = pbest[row];
    float s2 = psec[row];
    int ix = pidx[row];
#pragma unroll
    for (int h = 1; h < KSPLIT; ++h) {
      size_t o = (size_t)h * 65536 + row;
      float bh = pbest[o];
      float sh = psec[o];
      int ih = pidx[o];
      s2 = fminf(fminf(s2, sh), fmaxf(b, bh));
      if (bh < b) ix = ih;  // strict <: ties keep lower-half (smaller) index
      b = fminf(b, bh);
    }
    best_idx[row] = ix;
    if (s2 - b < MARGIN) {
      int slot = atomicAdd(&wn, 1);  // LDS atomic
      wl[slot] = row;
    }
  }
  __syncthreads();  // wl complete; merge-phase global stores drained (vmcnt)

  const int n = wn;
  const int wave = tid >> 6;
  const int lane = tid & 63;

  for (int j = wave; j < n; j += 4) {
    const int row = wl[j];
    if (lane < 16) ((f32x4*)zs[wave])[lane] = *((const f32x4*)(z_e + (size_t)row * D) + lane);

    float pb[KSPLIT], ps[KSPLIT];
    int pi[KSPLIT];
    float B = __builtin_inff();
#pragma unroll
    for (int h = 0; h < KSPLIT; ++h) {
      size_t o = (size_t)h * 65536 + row;
      pb[h] = pbest[o];
      ps[h] = psec[o];
      pi[h] = pidx[o];
      B = fminf(B, pb[h]);
    }
    const float lim = B + MARGIN;

    float bv = __builtin_inff();
    int bi = 0;
#pragma unroll
    for (int h = 0; h < KSPLIT; ++h) {
      if (ps[h] < lim) {
        // exact fp32 scan of this 1024-code half
        float hb = __builtin_inff();
        int hx = 0;
        for (int t = 0; t < 16; ++t) {
          int c = h * 1024 + t * 64 + lane;
          const f32x4* er = (const f32x4*)(emb + (size_t)c * D);
          f32x4 a = {0.f, 0.f, 0.f, 0.f};
#pragma unroll
          for (int i = 0; i < 16; ++i)
            a = __builtin_elementwise_fma(er[i], ((const f32x4*)zs[wave])[i], a);
          float dot = (a[0] + a[1]) + (a[2] + a[3]);
          float q = fmaf(-2.f, dot, esq[c]);
          if (q < hb) { hb = q; hx = c; }  // ascending t => first occurrence
        }
#pragma unroll
        for (int off = 32; off > 0; off >>= 1) {
          float ov = __shfl_down(hb, off);
          int oi = __shfl_down(hx, off);
          if (ov < hb || (ov == hb && oi < hx)) { hb = ov; hx = oi; }
        }
        hb = __shfl(hb, 0);
        hx = __shfl(hx, 0);
        if (hb < bv || (hb == bv && hx < bi)) { bv = hb; bi = hx; }
      } else if (pb[h] < lim) {
        // single candidate: exact dot for code pi[h]
        int c = pi[h];
        float p = emb[(size_t)c * D + lane] * zs[wave][lane];
#pragma unroll
        for (int off = 1; off < 64; off <<= 1) p += __shfl_xor(p, off);
        float q = fmaf(-2.f, p, esq[c]);
        if (q < bv || (q == bv && c < bi)) { bv = q; bi = c; }
      }
    }
    if (lane == 0) best_idx[row] = bi;
  }
}

// ---------------------------------------------------------------------------
// Gather z_q, write z_q_st + indices, loss partials, histogram. (Field-tested;
// last-block stats fusion stays REVERTED: sync cost must be O(blocks).)
// ---------------------------------------------------------------------------
__global__ __launch_bounds__(256) void finalize_kernel(const float* __restrict__ z_e,
                                                       const float* __restrict__ emb,
                                                       const int* __restrict__ best_idx,
                                                       float* __restrict__ out_zq,
                                                       float* __restrict__ out_idx,
                                                       int* __restrict__ counts,
                                                       float* __restrict__ block_loss) {
  const int tid = threadIdx.x;
  const int wave = tid >> 6;
  const int lane = tid & 63;
  const int row = blockIdx.x * 4 + wave;

  int bidx = best_idx[row];
  float ze = z_e[(size_t)row * D + lane];
  float zq = emb[(size_t)bidx * D + lane];
  float st = ze + (zq - ze);  // straight-through, same formula as reference
  out_zq[(size_t)row * D + lane] = st;

  float diff = zq - ze;
  float sq = diff * diff;
#pragma unroll
  for (int off = 32; off > 0; off >>= 1) sq += __shfl_down(sq, off);

  __shared__ float ls[4];
  if (lane == 0) {
    ls[wave] = sq;
    out_idx[row] = (float)bidx;
    atomicAdd(&counts[bidx], 1);
  }
  __syncthreads();
  if (tid == 0) block_loss[blockIdx.x] = ls[0] + ls[1] + ls[2] + ls[3];
}

// ---------------------------------------------------------------------------
// Final scalars: commitment loss, perplexity, n_active. Single block.
// ---------------------------------------------------------------------------
__global__ __launch_bounds__(1024) void stats_kernel(const float* __restrict__ block_loss,
                                                     int nblocks,
                                                     const int* __restrict__ counts,
                                                     float* __restrict__ out_scalars,
                                                     int N) {
  const int tid = threadIdx.x;
  const int wave = tid >> 6;
  const int lane = tid & 63;

  float lsum = 0.f;
  for (int i = tid; i < nblocks; i += 1024) lsum += block_loss[i];

  float ent = 0.f;
  int act = 0;
  const float invN = 1.0f / (float)N;
  for (int k = tid; k < K; k += 1024) {
    float p = (float)counts[k] * invN;
    ent += p * logf(p + 1e-10f);
    act += (p > 0.001f) ? 1 : 0;
  }

#pragma unroll
  for (int off = 32; off > 0; off >>= 1) {
    lsum += __shfl_down(lsum, off);
    ent += __shfl_down(ent, off);
    act += __shfl_down(act, off);
  }

  __shared__ float sl[16], se[16];
  __shared__ int sa[16];
  if (lane == 0) { sl[wave] = lsum; se[wave] = ent; sa[wave] = act; }
  __syncthreads();
  if (tid == 0) {
    float L = 0.f, E = 0.f;
    int A = 0;
#pragma unroll
    for (int w = 0; w < 16; ++w) { L += sl[w]; E += se[w]; A += sa[w]; }
    out_scalars[0] = 0.25f * L / ((float)N * (float)D);  // commitment loss
    out_scalars[1] = expf(-E);                            // perplexity
    out_scalars[2] = (float)A;                            // n_active
  }
}

extern "C" void kernel_launch(void* const* d_in, const int* in_sizes, int n_in,
                              void* d_out, int out_size, void* d_ws, size_t ws_size,
                              hipStream_t stream) {
  const float* z_e = (const float*)d_in[0];
  const float* emb = (const float*)d_in[1];
  const int N = in_sizes[0] / D;  // 65536

  float* out = (float*)d_out;
  float* out_zq = out;
  float* out_idx = out + (size_t)N * D;
  float* out_scalars = out + (size_t)N * (D + 1);

  char* ws = (char*)d_ws;
  size_t o = 0;
  int* counts = (int*)(ws + o);      o += 16384;                  // 4096 ints
  o += 256;                                                       // (hole)
  float* esq = (float*)(ws + o);     o += 16384;                  // 4096 f32
  short* e_h = (short*)(ws + o);     o += (size_t)K * D * 2;      // 512 KB (fp16)
  o += 8192;                                                      // prefetch pad
  float* pbest = (float*)(ws + o);   o += (size_t)KSPLIT * N * 4; // 1 MB
  float* psec = (float*)(ws + o);    o += (size_t)KSPLIT * N * 4; // 1 MB
  int* pidx = (int*)(ws + o);        o += (size_t)KSPLIT * N * 4; // 1 MB
  int* best_idx = (int*)(ws + o);    o += (size_t)N * 4;          // 256 KB
  float* block_loss = (float*)(ws + o);                            // 64 KB

  esplit_kernel<<<(K / 16) * 2 * 64 / 256, 256, 0, stream>>>(emb, e_h, esq, counts);
  dist_kernel<<<dim3(N / 128, KSPLIT), 256, 0, stream>>>(z_e, e_h, esq,
                                                         pbest, psec, pidx);
  merge_resolve_kernel<<<N / 256, 256, 0, stream>>>(z_e, emb, esq, pbest, psec,
                                                    pidx, best_idx);
  finalize_kernel<<<N / 4, 256, 0, stream>>>(z_e, emb, best_idx, out_zq, out_idx,
                                             counts, block_loss);
  stats_kernel<<<1, 1024, 0, stream>>>(block_loss, N / 4, counts, out_scalars, N);
}